// Round 13
// baseline (287.125 us; speedup 1.0000x reference)
//
#include <hip/hip_runtime.h>
#include <hip/hip_bf16.h>

#define PCHUNK 2048
#define NBK 1024      // hist width (padded); used buckets = ceil(100000/128) = 782
#define BSZ 128       // nodes per bucket
#define CAP 2560      // per-bucket edge capacity (mean 2046, +11 sigma)

__device__ inline float bf2f(unsigned int u16) { return __uint_as_float(u16 << 16); }
__device__ inline unsigned short f2bf(float f) {
    __hip_bfloat16 b = __float2bfloat16(f);
    return *(unsigned short*)&b;
}

typedef __attribute__((ext_vector_type(8))) short v8s;
typedef __attribute__((ext_vector_type(4))) float v4f;

// ---- phase 1: partition edges into 128-node dst-buckets; also zeroes pool.
//      PCHUNK=2048 -> 782 blocks (~3/CU) so LDS-atomic chains are latency-hidden. ----
__global__ void k_partition(const int* __restrict__ src, const int* __restrict__ dst, int E,
                            int* __restrict__ bucket_cnt, unsigned int* __restrict__ buckets,
                            float* __restrict__ zero_base, int zero_count) {
    __shared__ int hist[NBK];
    __shared__ int shift[NBK];
    __shared__ int cursor[NBK];
    __shared__ unsigned int staged_e[PCHUNK];
    __shared__ unsigned short staged_b[PCHUNK];
    __shared__ int wtot[4];
    int t = threadIdx.x;
    int lane = t & 63, wave = t >> 6;
    int base = blockIdx.x * PCHUNK;
    for (int i = blockIdx.x * 256 + t; i < zero_count; i += gridDim.x * 256)
        zero_base[i] = 0.f;
    for (int i = t; i < NBK; i += 256) hist[i] = 0;
    __syncthreads();
    int nE = E - base; if (nE > PCHUNK) nE = PCHUNK;
    int dreg[8];
    #pragma unroll
    for (int j = 0; j < 8; ++j) {
        int ii = t + j * 256;
        dreg[j] = (ii < nE) ? dst[base + ii] : -1;
    }
    #pragma unroll
    for (int j = 0; j < 8; ++j)
        if (dreg[j] >= 0) atomicAdd(&hist[dreg[j] >> 7], 1);
    __syncthreads();
    int h0 = hist[4 * t], h1 = hist[4 * t + 1], h2 = hist[4 * t + 2], h3 = hist[4 * t + 3];
    int p1 = h0 + h1, p2 = p1 + h2, s = p2 + h3;
    int si = s;
    #pragma unroll
    for (int off = 1; off < 64; off <<= 1) {
        int u = __shfl_up(si, off, 64);
        if (lane >= off) si += u;
    }
    if (lane == 63) wtot[wave] = si;
    __syncthreads();
    int woff = 0;
    #pragma unroll
    for (int w2 = 0; w2 < 4; ++w2) woff += (w2 < wave) ? wtot[w2] : 0;
    int ebase = woff + si - s;
    int ex[4] = {ebase, ebase + h0, ebase + p1, ebase + p2};
    int cn[4] = {h0, h1, h2, h3};
    #pragma unroll
    for (int j = 0; j < 4; ++j) {
        int bidx = 4 * t + j;
        cursor[bidx] = ex[j];
        if (cn[j] > 0) {
            int g = atomicAdd(&bucket_cnt[bidx], cn[j]);
            shift[bidx] = g - ex[j];
        }
    }
    __syncthreads();
    #pragma unroll
    for (int j = 0; j < 8; ++j) {
        if (dreg[j] >= 0) {
            int e = base + t + j * 256;
            int d = dreg[j];
            int b = d >> 7;
            int r = atomicAdd(&cursor[b], 1);
            staged_e[r] = (unsigned int)src[e] | ((unsigned int)(d & (BSZ - 1)) << 24);
            staged_b[r] = (unsigned short)b;
        }
    }
    __syncthreads();
    for (int i = t; i < nE; i += 256) {
        int b = staged_b[i];
        buckets[(size_t)b * CAP + shift[b] + i] = staged_e[i];
    }
}

// ---- phase 2: per-bucket CSR build + fused xw1 (R9-proven) ----
__global__ void k_bucket_csr_xw1(const unsigned int* __restrict__ buckets,
                                 const int* __restrict__ bucket_cnt,
                                 int* __restrict__ offs, int* __restrict__ deg,
                                 float* __restrict__ dinv, int* __restrict__ csr,
                                 const float* __restrict__ x, const float* __restrict__ W1,
                                 unsigned short* __restrict__ A, int N) {
    __shared__ int dl[BSZ], cur[BSZ];
    __shared__ float dis[BSZ];
    __shared__ float W1s[6 * 64];
    __shared__ float xs[BSZ * 6];
    __shared__ int w0tot;
    int b = blockIdx.x, t = threadIdx.x;
    int nb0 = b * BSZ;
    for (int i = t; i < 6 * 64; i += 256) W1s[i] = W1[i];
    for (int i = t; i < BSZ * 6; i += 256) {
        int node = nb0 + i / 6;
        xs[i] = (node < N) ? x[(size_t)nb0 * 6 + i] : 0.f;
    }
    if (t < BSZ) dl[t] = 0;
    __syncthreads();
    int cnt = bucket_cnt[b];
    if (cnt > CAP) cnt = CAP;
    const unsigned int* bp = buckets + (size_t)b * CAP;
    for (int i = t; i < cnt; i += 256) atomicAdd(&dl[bp[i] >> 24], 1);
    __syncthreads();
    int lane = t & 63, wave = t >> 6;
    int v = (t < BSZ) ? dl[t] : 0;
    int si = v;
    #pragma unroll
    for (int off = 1; off < 64; off <<= 1) {
        int u = __shfl_up(si, off, 64);
        if (lane >= off) si += u;
    }
    if (t == 63) w0tot = si;
    __syncthreads();
    int ex = si - v + ((wave == 1) ? w0tot : 0);
    if (t < BSZ) {
        cur[t] = ex;
        float di = rsqrtf((float)v + 1.0f);
        dis[t] = di;
        int n = nb0 + t;
        if (n < N) { offs[n] = b * CAP + ex; deg[n] = v; dinv[n] = di; }
    }
    __syncthreads();
    int* cg = csr + (size_t)b * CAP;
    for (int i = t; i < cnt; i += 256) {
        unsigned int e = bp[i];
        int r = atomicAdd(&cur[e >> 24], 1);
        cg[r] = (int)(e & 0x00FFFFFFu);
    }
    int ch = t & 63, sub = t >> 6;
    for (int nl = sub; nl < BSZ; nl += 4) {
        int node = nb0 + nl;
        if (node < N) {
            float acc = 0.f;
            #pragma unroll
            for (int k = 0; k < 6; ++k) acc += xs[nl * 6 + k] * W1s[k * 64 + ch];
            A[(size_t)node * 64 + ch] = f2bf(acc * dis[nl]);
        }
    }
}

// ---- pull conv1 + fused xw2 MFMA (4 ch/lane, R12-proven; CONTROL for 8ch test) ----
__global__ void k_pull1_xw2(const unsigned short* __restrict__ A, const int* __restrict__ csr,
                            const int* __restrict__ offs, const int* __restrict__ deg,
                            const float* __restrict__ dinv, const float* __restrict__ bias,
                            const float* __restrict__ W2, unsigned short* __restrict__ A2,
                            int N) {
    __shared__ unsigned short Ht[16][72];
    int t = threadIdx.x;
    int lane = t & 63, wave = t >> 6;
    int q = lane >> 4, m = lane & 15;
    int cbase = wave * 16;
    v8s b0h, b0l, b1h, b1l;
    #pragma unroll
    for (int j = 0; j < 8; ++j) {
        float w0 = W2[(q * 8 + j) * 64 + cbase + m];
        unsigned short h0 = f2bf(w0);
        b0h[j] = (short)h0;
        b0l[j] = (short)f2bf(w0 - bf2f(h0));
        float w1 = W2[(32 + q * 8 + j) * 64 + cbase + m];
        unsigned short h1 = f2bf(w1);
        b1h[j] = (short)h1;
        b1l[j] = (short)f2bf(w1 - bf2f(h1));
    }
    int n0 = blockIdx.x * 16;
    int nl = wave * 4 + q;
    int n = n0 + nl;
    bool valid = n < N;
    int nc = valid ? n : N - 1;
    int base = offs[nc];
    int dg = valid ? deg[nc] : 0;
    int dgm = dg, o;
    o = __shfl_xor(dgm, 16, 64); dgm = dgm > o ? dgm : o;
    o = __shfl_xor(dgm, 32, 64); dgm = dgm > o ? dgm : o;
    uint2 su = *(const uint2*)(A + ((size_t)nc << 6) + 4 * m);
    float a0 = __uint_as_float(su.x << 16);
    float a1 = __uint_as_float(su.x & 0xffff0000u);
    float a2 = __uint_as_float(su.y << 16);
    float a3 = __uint_as_float(su.y & 0xffff0000u);
    int i = 0;
    for (; i + 8 <= dgm; i += 8) {
        uint2 u[8];
        #pragma unroll
        for (int j = 0; j < 8; ++j) {
            unsigned int s = (unsigned int)csr[base + i + j];
            if (s >= (unsigned int)N) s = 0;
            u[j] = *(const uint2*)(A + ((size_t)s << 6) + 4 * m);
        }
        #pragma unroll
        for (int j = 0; j < 8; ++j) {
            unsigned int ux = (i + j < dg) ? u[j].x : 0u;
            unsigned int uy = (i + j < dg) ? u[j].y : 0u;
            a0 += __uint_as_float(ux << 16);
            a1 += __uint_as_float(ux & 0xffff0000u);
            a2 += __uint_as_float(uy << 16);
            a3 += __uint_as_float(uy & 0xffff0000u);
        }
    }
    for (; i < dgm; ++i) {
        unsigned int s = (unsigned int)csr[base + i];
        if (s >= (unsigned int)N) s = 0;
        uint2 uu = *(const uint2*)(A + ((size_t)s << 6) + 4 * m);
        unsigned int ux = (i < dg) ? uu.x : 0u;
        unsigned int uy = (i < dg) ? uu.y : 0u;
        a0 += __uint_as_float(ux << 16);
        a1 += __uint_as_float(ux & 0xffff0000u);
        a2 += __uint_as_float(uy << 16);
        a3 += __uint_as_float(uy & 0xffff0000u);
    }
    float di = valid ? dinv[n] : 0.f;
    float4 bb = *(const float4*)(bias + 4 * m);
    float v0 = fmaxf(fmaf(di, a0, bb.x), 0.f);
    float v1 = fmaxf(fmaf(di, a1, bb.y), 0.f);
    float v2 = fmaxf(fmaf(di, a2, bb.z), 0.f);
    float v3 = fmaxf(fmaf(di, a3, bb.w), 0.f);
    if (valid) {
        uint2 pk;
        pk.x = (unsigned int)f2bf(v0) | ((unsigned int)f2bf(v1) << 16);
        pk.y = (unsigned int)f2bf(v2) | ((unsigned int)f2bf(v3) << 16);
        *(uint2*)&Ht[nl][4 * m] = pk;
    }
    __syncthreads();
    union { uint4 u; v8s s; } a0u, a1u;
    a0u.u = *(const uint4*)&Ht[m][q * 8];
    a1u.u = *(const uint4*)&Ht[m][32 + q * 8];
    v4f acc = {0.f, 0.f, 0.f, 0.f};
    acc = __builtin_amdgcn_mfma_f32_16x16x32_bf16(a0u.s, b0l, acc, 0, 0, 0);
    acc = __builtin_amdgcn_mfma_f32_16x16x32_bf16(a1u.s, b1l, acc, 0, 0, 0);
    acc = __builtin_amdgcn_mfma_f32_16x16x32_bf16(a0u.s, b0h, acc, 0, 0, 0);
    acc = __builtin_amdgcn_mfma_f32_16x16x32_bf16(a1u.s, b1h, acc, 0, 0, 0);
    #pragma unroll
    for (int r = 0; r < 4; ++r) {
        int node = n0 + q * 4 + r;
        if (node < N)
            A2[(size_t)node * 64 + cbase + m] = f2bf(acc[r] * dinv[node]);
    }
}

// ---- pull conv2 + mean-pool. EXPERIMENT: 8 ch/lane (uint4), 8 nodes/wave,
//      32 nodes/block -> 0.25 VMEM instr/edge. LDS transpose keeps pool
//      atomics full-wave contiguous. ----
__global__ void k_pull_pool(const unsigned short* __restrict__ A, const int* __restrict__ csr,
                            const int* __restrict__ offs, const int* __restrict__ deg,
                            const float* __restrict__ dinv, const float* __restrict__ bias,
                            const int* __restrict__ batch, float* __restrict__ pool, int N) {
    __shared__ float vt[4][8][64];
    int t = threadIdx.x;
    int lane = t & 63, wave = t >> 6;
    int oct = lane >> 3, m = lane & 7;   // oct = node within wave, m = 8-ch group
    int n0 = blockIdx.x * 32;
    int nl = wave * 8 + oct;
    int n = n0 + nl;
    bool valid = n < N;
    int nc = valid ? n : N - 1;
    int base = offs[nc];
    int dg = valid ? deg[nc] : 0;
    int dgm = dg, o;
    o = __shfl_xor(dgm, 8, 64);  dgm = dgm > o ? dgm : o;
    o = __shfl_xor(dgm, 16, 64); dgm = dgm > o ? dgm : o;
    o = __shfl_xor(dgm, 32, 64); dgm = dgm > o ? dgm : o;
    uint4 su = *(const uint4*)(A + ((size_t)nc << 6) + 8 * m);
    float a0 = __uint_as_float(su.x << 16);
    float a1 = __uint_as_float(su.x & 0xffff0000u);
    float a2 = __uint_as_float(su.y << 16);
    float a3 = __uint_as_float(su.y & 0xffff0000u);
    float a4 = __uint_as_float(su.z << 16);
    float a5 = __uint_as_float(su.z & 0xffff0000u);
    float a6 = __uint_as_float(su.w << 16);
    float a7 = __uint_as_float(su.w & 0xffff0000u);
    int i = 0;
    for (; i + 8 <= dgm; i += 8) {
        uint4 u[8];
        #pragma unroll
        for (int j = 0; j < 8; ++j) {
            unsigned int s = (unsigned int)csr[base + i + j];
            if (s >= (unsigned int)N) s = 0;
            u[j] = *(const uint4*)(A + ((size_t)s << 6) + 8 * m);
        }
        #pragma unroll
        for (int j = 0; j < 8; ++j) {
            bool in = (i + j < dg);
            unsigned int ux = in ? u[j].x : 0u;
            unsigned int uy = in ? u[j].y : 0u;
            unsigned int uz = in ? u[j].z : 0u;
            unsigned int uw = in ? u[j].w : 0u;
            a0 += __uint_as_float(ux << 16);
            a1 += __uint_as_float(ux & 0xffff0000u);
            a2 += __uint_as_float(uy << 16);
            a3 += __uint_as_float(uy & 0xffff0000u);
            a4 += __uint_as_float(uz << 16);
            a5 += __uint_as_float(uz & 0xffff0000u);
            a6 += __uint_as_float(uw << 16);
            a7 += __uint_as_float(uw & 0xffff0000u);
        }
    }
    for (; i < dgm; ++i) {
        unsigned int s = (unsigned int)csr[base + i];
        if (s >= (unsigned int)N) s = 0;
        uint4 uu = *(const uint4*)(A + ((size_t)s << 6) + 8 * m);
        bool in = (i < dg);
        unsigned int ux = in ? uu.x : 0u;
        unsigned int uy = in ? uu.y : 0u;
        unsigned int uz = in ? uu.z : 0u;
        unsigned int uw = in ? uu.w : 0u;
        a0 += __uint_as_float(ux << 16);
        a1 += __uint_as_float(ux & 0xffff0000u);
        a2 += __uint_as_float(uy << 16);
        a3 += __uint_as_float(uy & 0xffff0000u);
        a4 += __uint_as_float(uz << 16);
        a5 += __uint_as_float(uz & 0xffff0000u);
        a6 += __uint_as_float(uw << 16);
        a7 += __uint_as_float(uw & 0xffff0000u);
    }
    float di = valid ? dinv[n] : 0.f;
    float4 bx = *(const float4*)(bias + 8 * m);
    float4 by = *(const float4*)(bias + 8 * m + 4);
    float4 vx, vy;
    vx.x = fmaxf(fmaf(di, a0, bx.x), 0.f);
    vx.y = fmaxf(fmaf(di, a1, bx.y), 0.f);
    vx.z = fmaxf(fmaf(di, a2, bx.z), 0.f);
    vx.w = fmaxf(fmaf(di, a3, bx.w), 0.f);
    vy.x = fmaxf(fmaf(di, a4, by.x), 0.f);
    vy.y = fmaxf(fmaf(di, a5, by.y), 0.f);
    vy.z = fmaxf(fmaf(di, a6, by.z), 0.f);
    vy.w = fmaxf(fmaf(di, a7, by.w), 0.f);
    *(float4*)&vt[wave][oct][8 * m] = vx;
    *(float4*)&vt[wave][oct][8 * m + 4] = vy;
    __syncthreads();
    int nw0 = n0 + wave * 8;
    #pragma unroll
    for (int r = 0; r < 8; ++r) {
        int nn = nw0 + r;
        if (nn < N) {
            float v = vt[wave][r][lane];
            atomicAdd(&pool[(size_t)batch[nn] * 64 + lane], v);
        }
    }
}

// per-graph head, 4 graphs per block; lin1W staged in LDS
__global__ void k_final4(const float* __restrict__ pool, const int* __restrict__ batch,
                         int N, int G,
                         const int* __restrict__ lig, const int* __restrict__ add,
                         const int* __restrict__ base, const int* __restrict__ aryl,
                         const float* __restrict__ e_lig, const float* __restrict__ e_add,
                         const float* __restrict__ e_base, const float* __restrict__ e_aryl,
                         const float* __restrict__ lin1W, const float* __restrict__ lin1b,
                         const float* __restrict__ lin2W, const float* __restrict__ lin2b,
                         float* __restrict__ out) {
    __shared__ float Wl[128 * 64];
    __shared__ float cat[4][128];
    int t = threadIdx.x;
    int c = t & 63, wv = t >> 6;
    for (int i = t; i < 128 * 64; i += 256) Wl[i] = lin1W[i];
    int g = blockIdx.x * 4 + wv;
    if (g < G) {
        int res = 0;
        if (c < 2) {
            int target = g + c;
            int lo = 0, hi = N;
            while (lo < hi) {
                int mid = (lo + hi) >> 1;
                if (batch[mid] < target) lo = mid + 1; else hi = mid;
            }
            res = lo;
        }
        int lo = __shfl(res, 0, 64), hi = __shfl(res, 1, 64);
        float invc = 1.0f / fmaxf((float)(hi - lo), 1.0f);
        cat[wv][c] = pool[(size_t)g * 64 + c] * invc;
        float ev;
        if (c < 16)      ev = e_lig[lig[g] * 16 + c];
        else if (c < 32) ev = e_add[add[g] * 16 + (c - 16)];
        else if (c < 48) ev = e_base[base[g] * 16 + (c - 32)];
        else             ev = e_aryl[aryl[g] * 16 + (c - 48)];
        cat[wv][64 + c] = ev;
    }
    __syncthreads();
    if (g < G) {
        float acc = lin1b[c];
        #pragma unroll
        for (int k = 0; k < 128; ++k) acc += cat[wv][k] * Wl[k * 64 + c];
        float p = fmaxf(acc, 0.f) * lin2W[c];
        #pragma unroll
        for (int off = 32; off > 0; off >>= 1) p += __shfl_down(p, off, 64);
        if (c == 0) out[g] = p + lin2b[0];
    }
}

extern "C" void kernel_launch(void* const* d_in, const int* in_sizes, int n_in,
                              void* d_out, int out_size, void* d_ws, size_t ws_size,
                              hipStream_t stream) {
    const float* x      = (const float*)d_in[0];
    const int*   ei     = (const int*)d_in[1];
    const int*   batch  = (const int*)d_in[2];
    const int*   lig    = (const int*)d_in[3];
    const int*   addi   = (const int*)d_in[4];
    const int*   basei  = (const int*)d_in[5];
    const int*   aryl   = (const int*)d_in[6];
    const float* e_lig  = (const float*)d_in[7];
    const float* e_add  = (const float*)d_in[8];
    const float* e_base = (const float*)d_in[9];
    const float* e_aryl = (const float*)d_in[10];
    const float* W1     = (const float*)d_in[11];
    const float* b1     = (const float*)d_in[12];
    const float* W2     = (const float*)d_in[13];
    const float* b2     = (const float*)d_in[14];
    const float* lin1W  = (const float*)d_in[15];
    const float* lin1b  = (const float*)d_in[16];
    const float* lin2W  = (const float*)d_in[17];
    const float* lin2b  = (const float*)d_in[18];
    float* out = (float*)d_out;

    const int N = in_sizes[0] / 6;
    const int E = in_sizes[1] / 2;
    const int G = in_sizes[3];
    const int* src = ei;
    const int* dst = ei + E;
    const int NBb = (N + BSZ - 1) / BSZ;   // 782 buckets

    // ---- workspace layout ----
    char* w = (char*)d_ws;
    size_t SA = (size_t)N * 64;
    unsigned short* A  = (unsigned short*)w;  w += SA * 2;  // Abar conv1 (bf16)
    unsigned short* A2 = (unsigned short*)w;  w += SA * 2;  // Abar conv2 (bf16)
    float* dinv = (float*)w;   w += (size_t)N * 4;
    int*   deg  = (int*)w;     w += (size_t)N * 4;
    int*   offs = (int*)w;     w += (size_t)N * 4;
    float* pool = (float*)w;   w += (size_t)G * 64 * 4;     // zeroed by k_partition
    int* bucket_cnt = (int*)w; w += NBK * 4;                // zeroed by memset
    unsigned int* buckets = (unsigned int*)w;  w += (size_t)NBb * CAP * 4;
    int* csr    = (int*)w;     w += (size_t)NBb * CAP * 4;
    w += 4096;   // slack: packed pulls read up to dgm past a node's csr end

    hipMemsetAsync(bucket_cnt, 0, NBK * 4, stream);

    const int npart = (E + PCHUNK - 1) / PCHUNK;   // 782 blocks
    k_partition<<<npart, 256, 0, stream>>>(src, dst, E, bucket_cnt, buckets,
                                           pool, G * 64);
    k_bucket_csr_xw1<<<NBb, 256, 0, stream>>>(buckets, bucket_cnt,
                                              offs, deg, dinv, csr, x, W1, A, N);

    // conv1 pull (4ch/lane, control) + fused xw2 MFMA
    k_pull1_xw2<<<(N + 15) / 16, 256, 0, stream>>>(A, csr, offs, deg, dinv, b1, W2, A2, N);

    // conv2 + fused pooling (8ch/lane experiment)
    k_pull_pool<<<(N + 31) / 32, 256, 0, stream>>>(A2, csr, offs, deg, dinv, b2, batch, pool, N);

    // head (4 graphs per block)
    k_final4<<<(G + 3) / 4, 256, 0, stream>>>(pool, batch, N, G, lig, addi, basei, aryl,
                                              e_lig, e_add, e_base, e_aryl,
                                              lin1W, lin1b, lin2W, lin2b, out);
}